// Round 1
// baseline (221.613 us; speedup 1.0000x reference)
//
#include <hip/hip_runtime.h>

// AttentionGCN forward, f32 throughout.
// B=32, N=1024, F=64, PRE=64, L1=128. Output y[32].
//
// Pipeline (all on `stream`, deterministic, no atomics):
//   k_deg      : d_isqrt[b,n] = rsqrt(rowsum(A)) (deg==0 -> 1)
//   k_spmm     : h = alpha*x + d_i * A * (d_j * x)   (register-tiled SGEMM, 64x64 tile)
//   k_values   : values = relu(h @ Wpre^T + bpre)
//   k_queries  : logits = relu(values @ Wfc1^T + bfc1) @ Wkeys^T + bkeys (queries never materialized)
//   k_softmax  : scores = softmax(logits / sqrt(2)) per batch
//   k_pool     : vpart[b,chunk,:] = partial sum over 64-node chunk of scores[n]*values[n,:]
//   k_out      : y[b] = (sum_chunk vpart) . Wout + bout

#define N_ 1024
#define F_ 64

__device__ __forceinline__ void fma_row(float (&a)[4], const float4 av,
                                        const float4 x0, const float4 x1,
                                        const float4 x2, const float4 x3) {
  a[0] += av.x * x0.x + av.y * x1.x + av.z * x2.x + av.w * x3.x;
  a[1] += av.x * x0.y + av.y * x1.y + av.z * x2.y + av.w * x3.y;
  a[2] += av.x * x0.z + av.y * x1.z + av.z * x2.z + av.w * x3.z;
  a[3] += av.x * x0.w + av.y * x1.w + av.z * x2.w + av.w * x3.w;
}

// ---------------- degree + d^-1/2 ----------------
__global__ __launch_bounds__(256) void k_deg(const float* __restrict__ A,
                                             float* __restrict__ disq) {
  const int row  = blockIdx.x * 4 + (threadIdx.x >> 6);   // global row in [0, B*N)
  const int lane = threadIdx.x & 63;
  const float4* a4 = (const float4*)(A + (size_t)row * N_);
  float s = 0.f;
#pragma unroll
  for (int it = 0; it < 4; ++it) {
    float4 v = a4[it * 64 + lane];
    s += v.x + v.y + v.z + v.w;
  }
#pragma unroll
  for (int off = 32; off > 0; off >>= 1) s += __shfl_down(s, off, 64);
  if (lane == 0) {
    float d = (s != 0.f) ? s : 1.f;
    disq[row] = rsqrtf(d);
  }
}

// ---------------- h = alpha*x + Anorm @ x ----------------
// Block: 256 threads, one batch, 64 output rows x 64 cols (F). K-tiles of 64.
__global__ __launch_bounds__(256) void k_spmm(const float* __restrict__ A,
                                              const float* __restrict__ x,
                                              const float* __restrict__ disq,
                                              const float* __restrict__ alphap,
                                              float* __restrict__ h) {
  __shared__ float as_[64][68];   // A tile, row-major, +4 pad
  __shared__ float xs_[64][64];   // (d_j * x) tile
  const int t  = threadIdx.x;
  const int b  = blockIdx.y;
  const int i0 = blockIdx.x * 64;
  const int cg = t & 15, rg = t >> 4;
  const float* Ab = A + ((size_t)b << 20);
  const float* xb = x + ((size_t)b << 16);
  const float* dq = disq + (b << 10);
  float acc[4][4] = {{0.f}};

  for (int j0 = 0; j0 < N_; j0 += 64) {
    __syncthreads();  // previous tile's reads done before overwrite
#pragma unroll
    for (int it = 0; it < 4; ++it) {
      int idx = it * 1024 + t * 4;
      int jj = idx >> 6, c4 = idx & 63;
      float4 v = *(const float4*)&xb[(size_t)(j0 + jj) * F_ + c4];
      float sc = dq[j0 + jj];
      v.x *= sc; v.y *= sc; v.z *= sc; v.w *= sc;
      *(float4*)&xs_[jj][c4] = v;
    }
#pragma unroll
    for (int it = 0; it < 4; ++it) {
      int idx = it * 1024 + t * 4;
      int ii = idx >> 6, jj = idx & 63;
      *(float4*)&as_[ii][jj] = *(const float4*)&Ab[(size_t)(i0 + ii) * N_ + j0 + jj];
    }
    __syncthreads();
#pragma unroll
    for (int q = 0; q < 16; ++q) {
      float4 xv0 = *(float4*)&xs_[q * 4 + 0][cg * 4];
      float4 xv1 = *(float4*)&xs_[q * 4 + 1][cg * 4];
      float4 xv2 = *(float4*)&xs_[q * 4 + 2][cg * 4];
      float4 xv3 = *(float4*)&xs_[q * 4 + 3][cg * 4];
#pragma unroll
      for (int k = 0; k < 4; ++k) {
        float4 av = *(float4*)&as_[rg * 4 + k][q * 4];
        fma_row(acc[k], av, xv0, xv1, xv2, xv3);
      }
    }
  }

  const float alpha = alphap[0];
#pragma unroll
  for (int k = 0; k < 4; ++k) {
    int r = i0 + rg * 4 + k;
    float di = dq[r];
    float4 xv = *(const float4*)&xb[(size_t)r * F_ + cg * 4];
    float4 o;
    o.x = alpha * xv.x + di * acc[k][0];
    o.y = alpha * xv.y + di * acc[k][1];
    o.z = alpha * xv.z + di * acc[k][2];
    o.w = alpha * xv.w + di * acc[k][3];
    *(float4*)&h[((size_t)b << 16) + (size_t)r * F_ + cg * 4] = o;
  }
}

// ---------------- values = relu(h @ Wpre^T + bpre) ----------------
__global__ __launch_bounds__(256) void k_values(const float* __restrict__ h,
                                                const float* __restrict__ Wpre,
                                                const float* __restrict__ bpre,
                                                float* __restrict__ values) {
  __shared__ float hs[64][68];
  __shared__ float wpt[64][64];   // wpt[f][p] = Wpre[p][f]
  const int t = threadIdx.x;
  const size_t base = (size_t)blockIdx.x * (64 * 64);
  const int cg = t & 15, rg = t >> 4;
#pragma unroll
  for (int it = 0; it < 4; ++it) {
    int idx = it * 1024 + t * 4;
    *(float4*)&hs[idx >> 6][idx & 63] = *(const float4*)&h[base + idx];
    float4 w = *(const float4*)&Wpre[idx];
    int p = idx >> 6, f = idx & 63;
    wpt[f + 0][p] = w.x; wpt[f + 1][p] = w.y; wpt[f + 2][p] = w.z; wpt[f + 3][p] = w.w;
  }
  __syncthreads();
  float acc[4][4] = {{0.f}};
#pragma unroll
  for (int q = 0; q < 16; ++q) {
    float4 xv0 = *(float4*)&wpt[q * 4 + 0][cg * 4];
    float4 xv1 = *(float4*)&wpt[q * 4 + 1][cg * 4];
    float4 xv2 = *(float4*)&wpt[q * 4 + 2][cg * 4];
    float4 xv3 = *(float4*)&wpt[q * 4 + 3][cg * 4];
#pragma unroll
    for (int k = 0; k < 4; ++k) {
      float4 av = *(float4*)&hs[rg * 4 + k][q * 4];
      fma_row(acc[k], av, xv0, xv1, xv2, xv3);
    }
  }
  float4 bp = *(const float4*)&bpre[cg * 4];
#pragma unroll
  for (int k = 0; k < 4; ++k) {
    float4 o;
    o.x = fmaxf(acc[k][0] + bp.x, 0.f);
    o.y = fmaxf(acc[k][1] + bp.y, 0.f);
    o.z = fmaxf(acc[k][2] + bp.z, 0.f);
    o.w = fmaxf(acc[k][3] + bp.w, 0.f);
    *(float4*)&values[base + (size_t)(rg * 4 + k) * 64 + cg * 4] = o;
  }
}

// ------- logits = relu(values @ Wfc1^T + bfc1) @ Wkeys^T + bkeys -------
__global__ __launch_bounds__(256) void k_queries(const float* __restrict__ values,
                                                 const float* __restrict__ Wfc1,
                                                 const float* __restrict__ bfc1,
                                                 const float* __restrict__ Wkeys,
                                                 const float* __restrict__ bkeysp,
                                                 float* __restrict__ logits) {
  __shared__ float vs[64][68];
  __shared__ float wft[64][128];  // wft[p][l] = Wfc1[l][p]
  __shared__ float part[64][17];
  const int t = threadIdx.x;
  const size_t base = (size_t)blockIdx.x * (64 * 64);
  const int lg = t & 15, rg = t >> 4;
#pragma unroll
  for (int it = 0; it < 4; ++it) {
    int idx = it * 1024 + t * 4;
    *(float4*)&vs[idx >> 6][idx & 63] = *(const float4*)&values[base + idx];
  }
#pragma unroll
  for (int it = 0; it < 8; ++it) {
    int idx = it * 1024 + t * 4;
    int l = idx >> 6, p = idx & 63;
    float4 w = *(const float4*)&Wfc1[idx];
    wft[p + 0][l] = w.x; wft[p + 1][l] = w.y; wft[p + 2][l] = w.z; wft[p + 3][l] = w.w;
  }
  __syncthreads();
  float acc_a[4][4] = {{0.f}};
  float acc_b[4][4] = {{0.f}};
#pragma unroll
  for (int q = 0; q < 16; ++q) {
    float4 w0a = *(float4*)&wft[q * 4 + 0][lg * 8];
    float4 w0b = *(float4*)&wft[q * 4 + 0][lg * 8 + 4];
    float4 w1a = *(float4*)&wft[q * 4 + 1][lg * 8];
    float4 w1b = *(float4*)&wft[q * 4 + 1][lg * 8 + 4];
    float4 w2a = *(float4*)&wft[q * 4 + 2][lg * 8];
    float4 w2b = *(float4*)&wft[q * 4 + 2][lg * 8 + 4];
    float4 w3a = *(float4*)&wft[q * 4 + 3][lg * 8];
    float4 w3b = *(float4*)&wft[q * 4 + 3][lg * 8 + 4];
#pragma unroll
    for (int k = 0; k < 4; ++k) {
      float4 vv = *(float4*)&vs[rg * 4 + k][q * 4];
      fma_row(acc_a[k], vv, w0a, w1a, w2a, w3a);
      fma_row(acc_b[k], vv, w0b, w1b, w2b, w3b);
    }
  }
  float4 bfa = *(const float4*)&bfc1[lg * 8];
  float4 bfb = *(const float4*)&bfc1[lg * 8 + 4];
  float4 wka = *(const float4*)&Wkeys[lg * 8];
  float4 wkb = *(const float4*)&Wkeys[lg * 8 + 4];
#pragma unroll
  for (int k = 0; k < 4; ++k) {
    float lp = 0.f;
    lp += fmaxf(acc_a[k][0] + bfa.x, 0.f) * wka.x;
    lp += fmaxf(acc_a[k][1] + bfa.y, 0.f) * wka.y;
    lp += fmaxf(acc_a[k][2] + bfa.z, 0.f) * wka.z;
    lp += fmaxf(acc_a[k][3] + bfa.w, 0.f) * wka.w;
    lp += fmaxf(acc_b[k][0] + bfb.x, 0.f) * wkb.x;
    lp += fmaxf(acc_b[k][1] + bfb.y, 0.f) * wkb.y;
    lp += fmaxf(acc_b[k][2] + bfb.z, 0.f) * wkb.z;
    lp += fmaxf(acc_b[k][3] + bfb.w, 0.f) * wkb.w;
    part[rg * 4 + k][lg] = lp;
  }
  __syncthreads();
  if (t < 64) {
    float s = bkeysp[0];
#pragma unroll
    for (int g = 0; g < 16; ++g) s += part[t][g];
    logits[blockIdx.x * 64 + t] = s;
  }
}

// ---------------- softmax over N per batch ----------------
__global__ __launch_bounds__(256) void k_softmax(const float* __restrict__ logits,
                                                 float* __restrict__ scores) {
  const int b = blockIdx.x, t = threadIdx.x;
  __shared__ float red[4];
  const float isq2 = 0.70710678118654752f;
  const int base = b * 1024;
  float l0 = logits[base + t] * isq2;
  float l1 = logits[base + 256 + t] * isq2;
  float l2 = logits[base + 512 + t] * isq2;
  float l3 = logits[base + 768 + t] * isq2;
  float m = fmaxf(fmaxf(l0, l1), fmaxf(l2, l3));
#pragma unroll
  for (int off = 32; off > 0; off >>= 1) m = fmaxf(m, __shfl_xor(m, off, 64));
  if ((t & 63) == 0) red[t >> 6] = m;
  __syncthreads();
  m = fmaxf(fmaxf(red[0], red[1]), fmaxf(red[2], red[3]));
  float e0 = expf(l0 - m), e1 = expf(l1 - m), e2 = expf(l2 - m), e3 = expf(l3 - m);
  float s = e0 + e1 + e2 + e3;
#pragma unroll
  for (int off = 32; off > 0; off >>= 1) s += __shfl_xor(s, off, 64);
  __syncthreads();  // all reads of red (max) complete
  if ((t & 63) == 0) red[t >> 6] = s;
  __syncthreads();
  s = red[0] + red[1] + red[2] + red[3];
  float inv = 1.f / s;
  scores[base + t]       = e0 * inv;
  scores[base + 256 + t] = e1 * inv;
  scores[base + 512 + t] = e2 * inv;
  scores[base + 768 + t] = e3 * inv;
}

// ---------------- partial pooled vector ----------------
__global__ __launch_bounds__(256) void k_pool(const float* __restrict__ values,
                                              const float* __restrict__ scores,
                                              float* __restrict__ vpart) {
  const int b = blockIdx.y, chunk = blockIdx.x, t = threadIdx.x;
  const int c = t & 63, g = t >> 6;
  const int nbase = b * 1024 + chunk * 64;
  float acc = 0.f;
#pragma unroll
  for (int k = 0; k < 16; ++k) {
    int n = nbase + g + 4 * k;
    acc += scores[n] * values[(size_t)n * 64 + c];
  }
  __shared__ float red[4][64];
  red[g][c] = acc;
  __syncthreads();
  if (t < 64) vpart[(b * 16 + chunk) * 64 + t] = red[0][t] + red[1][t] + red[2][t] + red[3][t];
}

// ---------------- final y ----------------
__global__ __launch_bounds__(256) void k_out(const float* __restrict__ vpart,
                                             const float* __restrict__ Wout,
                                             const float* __restrict__ boutp,
                                             float* __restrict__ y) {
  const int t = threadIdx.x, w = t >> 6, lane = t & 63;
#pragma unroll
  for (int it = 0; it < 8; ++it) {
    int b = w * 8 + it;
    float v = 0.f;
#pragma unroll
    for (int ch = 0; ch < 16; ++ch) v += vpart[(b * 16 + ch) * 64 + lane];
    float p = v * Wout[lane];
#pragma unroll
    for (int off = 32; off > 0; off >>= 1) p += __shfl_down(p, off, 64);
    if (lane == 0) y[b] = p + boutp[0];
  }
}

extern "C" void kernel_launch(void* const* d_in, const int* in_sizes, int n_in,
                              void* d_out, int out_size, void* d_ws, size_t ws_size,
                              hipStream_t stream) {
  const float* x     = (const float*)d_in[0];
  const float* A     = (const float*)d_in[1];
  const float* alpha = (const float*)d_in[2];
  const float* Wpre  = (const float*)d_in[3];
  const float* bpre  = (const float*)d_in[4];
  const float* Wfc1  = (const float*)d_in[5];
  const float* bfc1  = (const float*)d_in[6];
  const float* Wkeys = (const float*)d_in[7];
  const float* bkeys = (const float*)d_in[8];
  const float* Wout  = (const float*)d_in[9];
  const float* bout  = (const float*)d_in[10];
  float* y = (float*)d_out;

  float* ws     = (float*)d_ws;
  float* disq   = ws;                  // 32768 floats
  float* h      = disq + 32768;        // 2097152
  float* values = h + 2097152;         // 2097152
  float* logits = values + 2097152;    // 32768
  float* scores = logits + 32768;      // 32768
  float* vpart  = scores + 32768;      // 32768  (total ~17.3 MB)

  k_deg    <<<dim3(8192),    dim3(256), 0, stream>>>(A, disq);
  k_spmm   <<<dim3(16, 32),  dim3(256), 0, stream>>>(A, x, disq, alpha, h);
  k_values <<<dim3(512),     dim3(256), 0, stream>>>(h, Wpre, bpre, values);
  k_queries<<<dim3(512),     dim3(256), 0, stream>>>(values, Wfc1, bfc1, Wkeys, bkeys, logits);
  k_softmax<<<dim3(32),      dim3(256), 0, stream>>>(logits, scores);
  k_pool   <<<dim3(16, 32),  dim3(256), 0, stream>>>(values, scores, vpart);
  k_out    <<<dim3(1),       dim3(256), 0, stream>>>(vpart, Wout, bout, y);
}

// Round 2
// 107.040 us; speedup vs baseline: 2.0704x; 2.0704x over previous
//
#include <hip/hip_runtime.h>

// AttentionGCN forward. B=32, N=1024, F=64, PRE=64, L1=128. Output y[32].
//
// Pipeline (deterministic, no atomics):
//   k_deg       : disq[b,n] = rsqrt(rowsum(A)); reads A f32 once (A then L3-resident)
//   k_xt        : xtb[b,f,j] = bf16(disq[b,j] * x[b,j,f])   (transposed B operand)
//   k_spmm_mfma : h = alpha*x + d_i * (A @ (d_j x)) via bf16 MFMA, A converted f32->bf16 in-reg
//   k_values    : values = relu(h @ Wpre^T + bpre)          (in-place over h)
//   k_queries   : logits = relu(values @ Wfc1^T + bfc1) @ Wkeys^T + bkeys
//   k_softmax   : scores = softmax(logits / sqrt(2))        (in-place over logits)
//   k_pool      : per-64-node-chunk partial of scores[n]*values[n,:]
//   k_out       : y[b] = (sum_chunk vpart) . Wout + bout

#define N_ 1024
#define F_ 64

typedef short s16x8 __attribute__((ext_vector_type(8)));
typedef float f32x4 __attribute__((ext_vector_type(4)));
typedef unsigned short u16x8 __attribute__((ext_vector_type(8)));

__device__ __forceinline__ unsigned short bf16rne(float f) {
  union { float f; unsigned u; } v; v.f = f;
  unsigned r = v.u + 0x7fffu + ((v.u >> 16) & 1u);
  return (unsigned short)(r >> 16);
}

__device__ __forceinline__ void fma_row(float (&a)[4], const float4 av,
                                        const float4 x0, const float4 x1,
                                        const float4 x2, const float4 x3) {
  a[0] += av.x * x0.x + av.y * x1.x + av.z * x2.x + av.w * x3.x;
  a[1] += av.x * x0.y + av.y * x1.y + av.z * x2.y + av.w * x3.y;
  a[2] += av.x * x0.z + av.y * x1.z + av.z * x2.z + av.w * x3.z;
  a[3] += av.x * x0.w + av.y * x1.w + av.z * x2.w + av.w * x3.w;
}

// ---------------- degree + d^-1/2 (streams A once; warms L3) ----------------
__global__ __launch_bounds__(256) void k_deg(const float* __restrict__ A,
                                             float* __restrict__ disq) {
  const int row  = blockIdx.x * 4 + (threadIdx.x >> 6);   // [0, B*N)
  const int lane = threadIdx.x & 63;
  const float4* a4 = (const float4*)(A + (size_t)row * N_);
  float s = 0.f;
#pragma unroll
  for (int it = 0; it < 4; ++it) {
    float4 v = a4[it * 64 + lane];
    s += v.x + v.y + v.z + v.w;
  }
#pragma unroll
  for (int off = 32; off > 0; off >>= 1) s += __shfl_down(s, off, 64);
  if (lane == 0) {
    float d = (s != 0.f) ? s : 1.f;
    disq[row] = rsqrtf(d);
  }
}

// ---------------- xtb[b][f][j] = bf16(d_j * x[b][j][f]) ----------------
__global__ __launch_bounds__(256) void k_xt(const float* __restrict__ x,
                                            const float* __restrict__ disq,
                                            unsigned short* __restrict__ xtb) {
  __shared__ float xs[64][68];
  const int b = blockIdx.y, j0 = blockIdx.x * 64, t = threadIdx.x;
  const float* xb = x + ((size_t)b << 16);
  const float* dq = disq + (b << 10);
#pragma unroll
  for (int it = 0; it < 4; ++it) {
    int idx = it * 1024 + t * 4;
    int jj = idx >> 6, ff = idx & 63;
    float4 vv = *(const float4*)&xb[(size_t)(j0 + jj) * F_ + ff];
    float sc = dq[j0 + jj];
    vv.x *= sc; vv.y *= sc; vv.z *= sc; vv.w *= sc;
    *(float4*)&xs[jj][ff] = vv;
  }
  __syncthreads();
  const int f = t & 63, ch = t >> 6;
  u16x8 o0, o1;
#pragma unroll
  for (int jj = 0; jj < 8; ++jj) o0[jj] = bf16rne(xs[ch * 16 + jj][f]);
#pragma unroll
  for (int jj = 0; jj < 8; ++jj) o1[jj] = bf16rne(xs[ch * 16 + 8 + jj][f]);
  unsigned short* dst = xtb + (size_t)(b * 64 + f) * N_ + j0 + ch * 16;
  *(u16x8*)dst = o0;
  *(u16x8*)(dst + 8) = o1;
}

// ---------------- h = alpha*x + d_i * (A @ (d_j x)) via MFMA ----------------
// 4 waves/block; wave w owns 16 node-rows x 64 F. No LDS, no barriers.
// A fragment (16x16x32 bf16): lane l holds A[row = l&15][k = (l>>4)*8 + j], j=0..7
// B fragment: lane l holds B[k = (l>>4)*8 + j][col = l&15]  (from xtb row-contig)
// C/D: col = l&15, row = (l>>4)*4 + reg   [measured m89]
__global__ __launch_bounds__(256) void k_spmm_mfma(const float* __restrict__ A,
                                                   const unsigned short* __restrict__ xtb,
                                                   const float* __restrict__ x,
                                                   const float* __restrict__ disq,
                                                   const float* __restrict__ alphap,
                                                   float* __restrict__ h) {
  const int t = threadIdx.x;
  const int b = blockIdx.y;
  const int w = t >> 6, l = t & 63;
  const int rbase = blockIdx.x * 64 + w * 16;
  const int lr = l & 15, lk = (l >> 4) * 8;
  const float* Ap = A + ((size_t)b << 20) + (size_t)(rbase + lr) * N_ + lk;
  const unsigned short* Bp0 = xtb + (size_t)(b * 64 + 0  + lr) * N_ + lk;
  const unsigned short* Bp1 = xtb + (size_t)(b * 64 + 16 + lr) * N_ + lk;
  const unsigned short* Bp2 = xtb + (size_t)(b * 64 + 32 + lr) * N_ + lk;
  const unsigned short* Bp3 = xtb + (size_t)(b * 64 + 48 + lr) * N_ + lk;
  f32x4 acc0 = {0.f, 0.f, 0.f, 0.f}, acc1 = acc0, acc2 = acc0, acc3 = acc0;
#pragma unroll 4
  for (int k0 = 0; k0 < N_; k0 += 32) {
    float4 a0 = *(const float4*)(Ap + k0);
    float4 a1 = *(const float4*)(Ap + k0 + 4);
    s16x8 bv0 = *(const s16x8*)(Bp0 + k0);
    s16x8 bv1 = *(const s16x8*)(Bp1 + k0);
    s16x8 bv2 = *(const s16x8*)(Bp2 + k0);
    s16x8 bv3 = *(const s16x8*)(Bp3 + k0);
    s16x8 af;
    af[0] = (short)bf16rne(a0.x); af[1] = (short)bf16rne(a0.y);
    af[2] = (short)bf16rne(a0.z); af[3] = (short)bf16rne(a0.w);
    af[4] = (short)bf16rne(a1.x); af[5] = (short)bf16rne(a1.y);
    af[6] = (short)bf16rne(a1.z); af[7] = (short)bf16rne(a1.w);
    acc0 = __builtin_amdgcn_mfma_f32_16x16x32_bf16(af, bv0, acc0, 0, 0, 0);
    acc1 = __builtin_amdgcn_mfma_f32_16x16x32_bf16(af, bv1, acc1, 0, 0, 0);
    acc2 = __builtin_amdgcn_mfma_f32_16x16x32_bf16(af, bv2, acc2, 0, 0, 0);
    acc3 = __builtin_amdgcn_mfma_f32_16x16x32_bf16(af, bv3, acc3, 0, 0, 0);
  }
  const float alpha = alphap[0];
  const float* dq = disq + (b << 10);
  const float* xb = x + ((size_t)b << 16);
  float* hb = h + ((size_t)b << 16);
  const int orow = blockIdx.x * 64 + w * 16 + (l >> 4) * 4;
#pragma unroll
  for (int r = 0; r < 4; ++r) {
    float di = dq[orow + r];
    size_t ro = (size_t)(orow + r) * F_;
    hb[ro + 0  + lr] = alpha * xb[ro + 0  + lr] + di * acc0[r];
    hb[ro + 16 + lr] = alpha * xb[ro + 16 + lr] + di * acc1[r];
    hb[ro + 32 + lr] = alpha * xb[ro + 32 + lr] + di * acc2[r];
    hb[ro + 48 + lr] = alpha * xb[ro + 48 + lr] + di * acc3[r];
  }
}

// ---------------- values = relu(h @ Wpre^T + bpre), in-place over h ----------------
__global__ __launch_bounds__(256) void k_values(const float* h,
                                                const float* __restrict__ Wpre,
                                                const float* __restrict__ bpre,
                                                float* values) {
  __shared__ float hs[64][68];
  __shared__ float wpt[64][64];   // wpt[f][p] = Wpre[p][f]
  const int t = threadIdx.x;
  const size_t base = (size_t)blockIdx.x * (64 * 64);
  const int cg = t & 15, rg = t >> 4;
#pragma unroll
  for (int it = 0; it < 4; ++it) {
    int idx = it * 1024 + t * 4;
    *(float4*)&hs[idx >> 6][idx & 63] = *(const float4*)&h[base + idx];
    float4 w = *(const float4*)&Wpre[idx];
    int p = idx >> 6, f = idx & 63;
    wpt[f + 0][p] = w.x; wpt[f + 1][p] = w.y; wpt[f + 2][p] = w.z; wpt[f + 3][p] = w.w;
  }
  __syncthreads();
  float acc[4][4] = {{0.f}};
#pragma unroll
  for (int q = 0; q < 16; ++q) {
    float4 xv0 = *(float4*)&wpt[q * 4 + 0][cg * 4];
    float4 xv1 = *(float4*)&wpt[q * 4 + 1][cg * 4];
    float4 xv2 = *(float4*)&wpt[q * 4 + 2][cg * 4];
    float4 xv3 = *(float4*)&wpt[q * 4 + 3][cg * 4];
#pragma unroll
    for (int k = 0; k < 4; ++k) {
      float4 av = *(float4*)&hs[rg * 4 + k][q * 4];
      fma_row(acc[k], av, xv0, xv1, xv2, xv3);
    }
  }
  float4 bp = *(const float4*)&bpre[cg * 4];
#pragma unroll
  for (int k = 0; k < 4; ++k) {
    float4 o;
    o.x = fmaxf(acc[k][0] + bp.x, 0.f);
    o.y = fmaxf(acc[k][1] + bp.y, 0.f);
    o.z = fmaxf(acc[k][2] + bp.z, 0.f);
    o.w = fmaxf(acc[k][3] + bp.w, 0.f);
    *(float4*)&values[base + (size_t)(rg * 4 + k) * 64 + cg * 4] = o;
  }
}

// ------- logits = relu(values @ Wfc1^T + bfc1) @ Wkeys^T + bkeys -------
__global__ __launch_bounds__(256) void k_queries(const float* __restrict__ values,
                                                 const float* __restrict__ Wfc1,
                                                 const float* __restrict__ bfc1,
                                                 const float* __restrict__ Wkeys,
                                                 const float* __restrict__ bkeysp,
                                                 float* __restrict__ logits) {
  __shared__ float vs[64][68];
  __shared__ float wft[64][128];  // wft[p][l] = Wfc1[l][p]
  __shared__ float part[64][17];
  const int t = threadIdx.x;
  const size_t base = (size_t)blockIdx.x * (64 * 64);
  const int lg = t & 15, rg = t >> 4;
#pragma unroll
  for (int it = 0; it < 4; ++it) {
    int idx = it * 1024 + t * 4;
    *(float4*)&vs[idx >> 6][idx & 63] = *(const float4*)&values[base + idx];
  }
#pragma unroll
  for (int it = 0; it < 8; ++it) {
    int idx = it * 1024 + t * 4;
    int l = idx >> 6, p = idx & 63;
    float4 w = *(const float4*)&Wfc1[idx];
    wft[p + 0][l] = w.x; wft[p + 1][l] = w.y; wft[p + 2][l] = w.z; wft[p + 3][l] = w.w;
  }
  __syncthreads();
  float acc_a[4][4] = {{0.f}};
  float acc_b[4][4] = {{0.f}};
#pragma unroll
  for (int q = 0; q < 16; ++q) {
    float4 w0a = *(float4*)&wft[q * 4 + 0][lg * 8];
    float4 w0b = *(float4*)&wft[q * 4 + 0][lg * 8 + 4];
    float4 w1a = *(float4*)&wft[q * 4 + 1][lg * 8];
    float4 w1b = *(float4*)&wft[q * 4 + 1][lg * 8 + 4];
    float4 w2a = *(float4*)&wft[q * 4 + 2][lg * 8];
    float4 w2b = *(float4*)&wft[q * 4 + 2][lg * 8 + 4];
    float4 w3a = *(float4*)&wft[q * 4 + 3][lg * 8];
    float4 w3b = *(float4*)&wft[q * 4 + 3][lg * 8 + 4];
#pragma unroll
    for (int k = 0; k < 4; ++k) {
      float4 vv = *(float4*)&vs[rg * 4 + k][q * 4];
      fma_row(acc_a[k], vv, w0a, w1a, w2a, w3a);
      fma_row(acc_b[k], vv, w0b, w1b, w2b, w3b);
    }
  }
  float4 bfa = *(const float4*)&bfc1[lg * 8];
  float4 bfb = *(const float4*)&bfc1[lg * 8 + 4];
  float4 wka = *(const float4*)&Wkeys[lg * 8];
  float4 wkb = *(const float4*)&Wkeys[lg * 8 + 4];
#pragma unroll
  for (int k = 0; k < 4; ++k) {
    float lp = 0.f;
    lp += fmaxf(acc_a[k][0] + bfa.x, 0.f) * wka.x;
    lp += fmaxf(acc_a[k][1] + bfa.y, 0.f) * wka.y;
    lp += fmaxf(acc_a[k][2] + bfa.z, 0.f) * wka.z;
    lp += fmaxf(acc_a[k][3] + bfa.w, 0.f) * wka.w;
    lp += fmaxf(acc_b[k][0] + bfb.x, 0.f) * wkb.x;
    lp += fmaxf(acc_b[k][1] + bfb.y, 0.f) * wkb.y;
    lp += fmaxf(acc_b[k][2] + bfb.z, 0.f) * wkb.z;
    lp += fmaxf(acc_b[k][3] + bfb.w, 0.f) * wkb.w;
    part[rg * 4 + k][lg] = lp;
  }
  __syncthreads();
  if (t < 64) {
    float s = bkeysp[0];
#pragma unroll
    for (int g = 0; g < 16; ++g) s += part[t][g];
    logits[blockIdx.x * 64 + t] = s;
  }
}

// ---------------- softmax over N per batch (in-place) ----------------
__global__ __launch_bounds__(256) void k_softmax(const float* logits,
                                                 float* scores) {
  const int b = blockIdx.x, t = threadIdx.x;
  __shared__ float red[4];
  const float isq2 = 0.70710678118654752f;
  const int base = b * 1024;
  float l0 = logits[base + t] * isq2;
  float l1 = logits[base + 256 + t] * isq2;
  float l2 = logits[base + 512 + t] * isq2;
  float l3 = logits[base + 768 + t] * isq2;
  float m = fmaxf(fmaxf(l0, l1), fmaxf(l2, l3));
#pragma unroll
  for (int off = 32; off > 0; off >>= 1) m = fmaxf(m, __shfl_xor(m, off, 64));
  if ((t & 63) == 0) red[t >> 6] = m;
  __syncthreads();
  m = fmaxf(fmaxf(red[0], red[1]), fmaxf(red[2], red[3]));
  float e0 = expf(l0 - m), e1 = expf(l1 - m), e2 = expf(l2 - m), e3 = expf(l3 - m);
  float s = e0 + e1 + e2 + e3;
#pragma unroll
  for (int off = 32; off > 0; off >>= 1) s += __shfl_xor(s, off, 64);
  __syncthreads();
  if ((t & 63) == 0) red[t >> 6] = s;
  __syncthreads();
  s = red[0] + red[1] + red[2] + red[3];
  float inv = 1.f / s;
  scores[base + t]       = e0 * inv;
  scores[base + 256 + t] = e1 * inv;
  scores[base + 512 + t] = e2 * inv;
  scores[base + 768 + t] = e3 * inv;
}

// ---------------- partial pooled vector ----------------
__global__ __launch_bounds__(256) void k_pool(const float* __restrict__ values,
                                              const float* __restrict__ scores,
                                              float* __restrict__ vpart) {
  const int b = blockIdx.y, chunk = blockIdx.x, t = threadIdx.x;
  const int c = t & 63, g = t >> 6;
  const int nbase = b * 1024 + chunk * 64;
  float acc = 0.f;
#pragma unroll
  for (int k = 0; k < 16; ++k) {
    int n = nbase + g + 4 * k;
    acc += scores[n] * values[(size_t)n * 64 + c];
  }
  __shared__ float red[4][64];
  red[g][c] = acc;
  __syncthreads();
  if (t < 64) vpart[(b * 16 + chunk) * 64 + t] = red[0][t] + red[1][t] + red[2][t] + red[3][t];
}

// ---------------- final y ----------------
__global__ __launch_bounds__(256) void k_out(const float* __restrict__ vpart,
                                             const float* __restrict__ Wout,
                                             const float* __restrict__ boutp,
                                             float* __restrict__ y) {
  const int t = threadIdx.x, w = t >> 6, lane = t & 63;
#pragma unroll
  for (int it = 0; it < 8; ++it) {
    int b = w * 8 + it;
    float v = 0.f;
#pragma unroll
    for (int ch = 0; ch < 16; ++ch) v += vpart[(b * 16 + ch) * 64 + lane];
    float p = v * Wout[lane];
#pragma unroll
    for (int off = 32; off > 0; off >>= 1) p += __shfl_down(p, off, 64);
    if (lane == 0) y[b] = p + boutp[0];
  }
}

extern "C" void kernel_launch(void* const* d_in, const int* in_sizes, int n_in,
                              void* d_out, int out_size, void* d_ws, size_t ws_size,
                              hipStream_t stream) {
  const float* x     = (const float*)d_in[0];
  const float* A     = (const float*)d_in[1];
  const float* alpha = (const float*)d_in[2];
  const float* Wpre  = (const float*)d_in[3];
  const float* bpre  = (const float*)d_in[4];
  const float* Wfc1  = (const float*)d_in[5];
  const float* bfc1  = (const float*)d_in[6];
  const float* Wkeys = (const float*)d_in[7];
  const float* bkeys = (const float*)d_in[8];
  const float* Wout  = (const float*)d_in[9];
  const float* bout  = (const float*)d_in[10];
  float* y = (float*)d_out;

  float* ws     = (float*)d_ws;
  float* disq   = ws;                   // 32768 f32
  float* hv     = disq + 32768;         // 2097152 f32 (h, then values in-place)
  float* logits = hv + 2097152;         // 32768 f32 (scores in-place)
  float* vpart  = logits + 32768;       // 32768 f32
  unsigned short* xtb = (unsigned short*)(vpart + 32768);  // 2097152 bf16 (4 MB)
  // total ~13 MB of ws

  k_deg      <<<dim3(8192),   dim3(256), 0, stream>>>(A, disq);
  k_xt       <<<dim3(16, 32), dim3(256), 0, stream>>>(x, disq, xtb);
  k_spmm_mfma<<<dim3(16, 32), dim3(256), 0, stream>>>(A, xtb, x, disq, alpha, hv);
  k_values   <<<dim3(512),    dim3(256), 0, stream>>>(hv, Wpre, bpre, hv);
  k_queries  <<<dim3(512),    dim3(256), 0, stream>>>(hv, Wfc1, bfc1, Wkeys, bkeys, logits);
  k_softmax  <<<dim3(32),     dim3(256), 0, stream>>>(logits, logits);
  k_pool     <<<dim3(16, 32), dim3(256), 0, stream>>>(hv, logits, vpart);
  k_out      <<<dim3(1),      dim3(256), 0, stream>>>(vpart, Wout, bout, y);
}